// Round 4
// baseline (98.343 us; speedup 1.0000x reference)
//
#include <hip/hip_runtime.h>
#include <cfloat>

// ChamferLossKL: bs=8, n=2048, d=4, fp32.
// p_kl[i][j] = 0.5 * s_ij,  s_ij = dot8(rowrec_i, colrec_j) + ca_i + cb_j
//   row (pred) A-record: pa = exp(lva)+mua^2 (4), mua (4), ca = -sum(lva)-4
//   col (gt)   B-record: ivb = exp(-lvb) (4), m2 = -2*mub*ivb (4),
//                        cb = sum(mub^2*ivb)+sum(lvb)
// loss[b] = 0.5*( sum_j min_i (dot+ca_i) + cb_j  +  sum_i min_j (dot+cb_j) + ca_i )
//
// R3->R4: (1) exploit that loss_1/loss_2 are col-min/row-min of the SAME
// matrix -> evaluate each pair once (was twice), computing both t=dot+cb
// (row-min, registers) and u=dot+ca (col-min, LDS ds_min_u32 on monotone
// uint encoding). (2) single dispatch: last-block-per-batch finalize via
// per-batch counters in d_ws (old&31==31 -> reducer; mod-32 trick is
// poison-proof). (3) float2-paired row chains to invite v_pk_fma_f32.

#define TPB    1024
#define WAVES  16
#define RPT    8
#define ROWSPB (WAVES * RPT)    // 128
#define NFIX   2048
#define CH_COLS (NFIX / 2)      // 1024 columns per block
#define NRG    (NFIX / ROWSPB)  // 16 row groups

__device__ __forceinline__ unsigned enc_f32(float f) {
    unsigned u = __float_as_uint(f);
    return (u & 0x80000000u) ? ~u : (u | 0x80000000u);
}
__device__ __forceinline__ float dec_f32(unsigned e) {
    return (e & 0x80000000u) ? __uint_as_float(e ^ 0x80000000u)
                             : __uint_as_float(~e);
}

__global__ __launch_bounds__(TPB) void chamfer_kl_onepass(
    const float4* __restrict__ mu_a, const float4* __restrict__ lv_a,
    const float4* __restrict__ mu_b, const float4* __restrict__ lv_b,
    float* __restrict__ rowpart,     // [8][2][2048]
    float* __restrict__ colpart,     // [8][16][2048]
    unsigned* __restrict__ counters, // [8]
    float* __restrict__ out)
{
    __shared__ float4   sv0[CH_COLS];   // ivb           16 KB
    __shared__ float4   sv1[CH_COLS];   // m2            16 KB
    __shared__ float    scb[CH_COLS];   // cb             4 KB
    __shared__ unsigned scm[CH_COLS];   // col-min enc    4 KB
    __shared__ float    fsum[WAVES];
    __shared__ unsigned sOld;

    const int t    = threadIdx.x;
    const int rg   = blockIdx.x;     // 16 row groups
    const int b    = blockIdx.y;     // 8 batches
    const int ch   = blockIdx.z;     // 2 column halves
    const int lane = t & 63;
    const int wid  = t >> 6;
    const int n    = NFIX;

    // ---- stage this half's column records (gts -> B-type)
    {
        const int j = ch * CH_COLS + t;
        float4 mu = mu_b[(size_t)b * n + j];
        float4 lv = lv_b[(size_t)b * n + j];
        float4 iv = make_float4(__expf(-lv.x), __expf(-lv.y),
                                __expf(-lv.z), __expf(-lv.w));
        sv0[t] = iv;
        sv1[t] = make_float4(-2.f * mu.x * iv.x, -2.f * mu.y * iv.y,
                             -2.f * mu.z * iv.z, -2.f * mu.w * iv.w);
        scb[t] = mu.x * mu.x * iv.x + mu.y * mu.y * iv.y
               + mu.z * mu.z * iv.z + mu.w * mu.w * iv.w
               + lv.x + lv.y + lv.z + lv.w;
        scm[t] = 0xFFFFFFFFu;
    }

    // ---- row records (preds -> A-type), 8 rows/thread, component-major pairs
    const int rbase = rg * ROWSPB + wid * RPT;
    float2 px[4], py[4], pz[4], pw[4];   // pa components
    float2 qx[4], qy[4], qz[4], qw[4];   // mua components
    float2 ca[4], rmin[4];
#pragma unroll
    for (int p = 0; p < 4; ++p) {
        float4 muA = mu_a[(size_t)b * n + rbase + 2 * p];
        float4 lvA = lv_a[(size_t)b * n + rbase + 2 * p];
        float4 muB = mu_a[(size_t)b * n + rbase + 2 * p + 1];
        float4 lvB = lv_a[(size_t)b * n + rbase + 2 * p + 1];
        px[p] = make_float2(__expf(lvA.x) + muA.x * muA.x, __expf(lvB.x) + muB.x * muB.x);
        py[p] = make_float2(__expf(lvA.y) + muA.y * muA.y, __expf(lvB.y) + muB.y * muB.y);
        pz[p] = make_float2(__expf(lvA.z) + muA.z * muA.z, __expf(lvB.z) + muB.z * muB.z);
        pw[p] = make_float2(__expf(lvA.w) + muA.w * muA.w, __expf(lvB.w) + muB.w * muB.w);
        qx[p] = make_float2(muA.x, muB.x);
        qy[p] = make_float2(muA.y, muB.y);
        qz[p] = make_float2(muA.z, muB.z);
        qw[p] = make_float2(muA.w, muB.w);
        ca[p] = make_float2(-(lvA.x + lvA.y + lvA.z + lvA.w) - 4.f,
                            -(lvB.x + lvB.y + lvB.z + lvB.w) - 4.f);
        rmin[p] = make_float2(FLT_MAX, FLT_MAX);
    }
    __syncthreads();

    // ---- main sweep: 128 rows x 1024 cols, each pair evaluated ONCE
#pragma unroll 2
    for (int jj = 0; jj < CH_COLS / 64; ++jj) {
        const int j = (jj << 6) + lane;
        const float4 c0 = sv0[j];
        const float4 c1 = sv1[j];
        const float  cb = scb[j];
        float2 cmin = make_float2(FLT_MAX, FLT_MAX);
#pragma unroll
        for (int p = 0; p < 4; ++p) {
            float2 s;
            s.x = px[p].x * c0.x;           s.y = px[p].y * c0.x;
            s.x = fmaf(py[p].x, c0.y, s.x); s.y = fmaf(py[p].y, c0.y, s.y);
            s.x = fmaf(pz[p].x, c0.z, s.x); s.y = fmaf(pz[p].y, c0.z, s.y);
            s.x = fmaf(pw[p].x, c0.w, s.x); s.y = fmaf(pw[p].y, c0.w, s.y);
            s.x = fmaf(qx[p].x, c1.x, s.x); s.y = fmaf(qx[p].y, c1.x, s.y);
            s.x = fmaf(qy[p].x, c1.y, s.x); s.y = fmaf(qy[p].y, c1.y, s.y);
            s.x = fmaf(qz[p].x, c1.z, s.x); s.y = fmaf(qz[p].y, c1.z, s.y);
            s.x = fmaf(qw[p].x, c1.w, s.x); s.y = fmaf(qw[p].y, c1.w, s.y);
            rmin[p].x = fminf(rmin[p].x, s.x + cb);
            rmin[p].y = fminf(rmin[p].y, s.y + cb);
            cmin.x = fminf(cmin.x, s.x + ca[p].x);
            cmin.y = fminf(cmin.y, s.y + ca[p].y);
        }
        atomicMin(&scm[j], enc_f32(fminf(cmin.x, cmin.y)));
    }
    __syncthreads();

    // ---- col partials (min over this block's 128 rows), coalesced
    colpart[((size_t)b * NRG + rg) * n + ch * CH_COLS + t] = dec_f32(scm[t]);

    // ---- row partials: min across 64 lanes, one slot per row
    {
        float* rp = rowpart + ((size_t)b * 2 + ch) * n + rbase;
#pragma unroll
        for (int p = 0; p < 4; ++p) {
            float mx = rmin[p].x, my = rmin[p].y;
#pragma unroll
            for (int off = 32; off; off >>= 1) {
                mx = fminf(mx, __shfl_xor(mx, off, 64));
                my = fminf(my, __shfl_xor(my, off, 64));
            }
            if (lane == 0) { rp[2 * p] = mx; rp[2 * p + 1] = my; }
        }
    }

    // ---- last block of this batch (32 blocks/batch) finalizes it.
    // mod-32 trick: works for ANY initial counter value (0xAA poison ok).
    __threadfence();
    if (t == 0)
        sOld = __hip_atomic_fetch_add(&counters[b], 1u,
                                      __ATOMIC_ACQ_REL, __HIP_MEMORY_SCOPE_AGENT);
    __syncthreads();
    if ((sOld & 31u) != 31u) return;
    __threadfence();

    float acc = 0.f;
    for (int j = t; j < n; j += TPB) {
        float m = FLT_MAX;
#pragma unroll
        for (int g = 0; g < NRG; ++g)
            m = fminf(m, colpart[((size_t)b * NRG + g) * n + j]);
        float4 mu = mu_b[(size_t)b * n + j];
        float4 lv = lv_b[(size_t)b * n + j];
        float ivx = __expf(-lv.x), ivy = __expf(-lv.y);
        float ivz = __expf(-lv.z), ivw = __expf(-lv.w);
        acc += m + mu.x * mu.x * ivx + mu.y * mu.y * ivy
             + mu.z * mu.z * ivz + mu.w * mu.w * ivw
             + lv.x + lv.y + lv.z + lv.w;
    }
    for (int i = t; i < n; i += TPB) {
        float m = fminf(rowpart[((size_t)b * 2 + 0) * n + i],
                        rowpart[((size_t)b * 2 + 1) * n + i]);
        float4 lv = lv_a[(size_t)b * n + i];
        acc += m - (lv.x + lv.y + lv.z + lv.w) - 4.f;
    }
#pragma unroll
    for (int off = 32; off; off >>= 1) acc += __shfl_xor(acc, off, 64);
    if (lane == 0) fsum[wid] = acc;
    __syncthreads();
    if (t < 64) {
        float v = (lane < WAVES) ? fsum[lane] : 0.f;
#pragma unroll
        for (int off = 8; off; off >>= 1) v += __shfl_xor(v, off, 64);
        if (t == 0) out[b] = 0.5f * v;
    }
}

extern "C" void kernel_launch(void* const* d_in, const int* in_sizes, int n_in,
                              void* d_out, int out_size, void* d_ws, size_t ws_size,
                              hipStream_t stream) {
    const float4* mu_a = (const float4*)d_in[0];  // mu_preds
    const float4* lv_a = (const float4*)d_in[1];  // logvar_preds
    const float4* mu_b = (const float4*)d_in[2];  // mu_gts
    const float4* lv_b = (const float4*)d_in[3];  // logvar_gts

    const int bs = out_size;  // 8

    float* ws = (float*)d_ws;
    float*    colpart  = ws;                                           // 8*16*2048
    float*    rowpart  = ws + (size_t)bs * NRG * NFIX;                 // 8*2*2048
    unsigned* counters = (unsigned*)(rowpart + (size_t)bs * 2 * NFIX); // 8

    dim3 grid(NRG, bs, 2);  // (16, 8, 2) = 256 blocks, 1/CU
    chamfer_kl_onepass<<<grid, TPB, 0, stream>>>(mu_a, lv_a, mu_b, lv_b,
                                                 rowpart, colpart, counters,
                                                 (float*)d_out);
}